// Round 4
// baseline (208.957 us; speedup 1.0000x reference)
//
#include <hip/hip_runtime.h>

typedef _Float16 half2_t __attribute__((ext_vector_type(2)));

#define SOS_IDX 1
#define EOS_IDX 2
#define B 32
#define T 256
#define K 128

#if __has_builtin(__builtin_amdgcn_fdot2)
__device__ __forceinline__ float dot2(half2_t a, half2_t b, float c) {
    return __builtin_amdgcn_fdot2(a, b, c, false);   // v_dot2_f32_f16
}
#else
__device__ __forceinline__ float dot2(half2_t a, half2_t b, float c) {
    return fmaf((float)a.x, (float)b.x, fmaf((float)a.y, (float)b.y, c));
}
#endif

union U4 { uint4 v; half2_t h[4]; };
union UW { unsigned u; half2_t h; };

// One block per batch, 256 threads = 4 waves. Lane pair (2u,2u+1) owns state u;
// lane half hf = tid&1 dots i in [64*hf, 64*hf+64).
//
// ET held as 32 packed f16x2 VGPRs per lane (rounds 1-3 evidence: the allocator
// spills any per-lane array needing >~56 total VGPRs, costing ~1000 cyc/step of
// scratch reload; 32+temps fits). v stored in LDS as f16x2, normalized per wave
// each step; per-wave residual scales m[4] (f32) make the dot exact:
//   s_j = eh_j * sum_c m_c * dot2(v_chunk_c, et_chunk_c)
// Running offset c += log(max m) keeps everything in f32 range. One barrier per
// step (double-buffered v,m).
__global__ __launch_bounds__(2 * K, 1) void crf_fused(const float* __restrict__ hin,
                                                      const float* __restrict__ trans,
                                                      const int* __restrict__ y,
                                                      const int* __restrict__ lengths,
                                                      float* __restrict__ out) {
    const int b   = blockIdx.x;
    const int tid = threadIdx.x;
    const int u   = tid >> 1;      // state owned by this lane pair
    const int hf  = tid & 1;       // i-half this lane dots
    const int w   = tid >> 6;      // wave index
    const int len = lengths[b];

    __shared__ __align__(16) unsigned vbuf[2][K / 2];  // f16x2: dword d = states (2d,2d+1)
    __shared__ __align__(16) float    mbuf[2][4];      // per-wave residual scales
    __shared__ float gred[4];

    // ---- gold path score (t = tid covers all T) ----
    float g = 0.0f;
    if (tid < len) {
        int yt   = y[b * T + tid];
        int prev = (tid == 0) ? SOS_IDX : y[b * T + tid - 1];
        g = hin[(b * T + tid) * K + yt] + trans[prev * K + yt];
    }
#pragma unroll
    for (int off = 32; off > 0; off >>= 1) g += __shfl_down(g, off);
    if ((tid & 63) == 0) gred[w] = g;

    // ---- half-column of exp(transition), packed f16x2 (32 VGPRs) ----
    half2_t et[32];
#pragma unroll
    for (int q = 0; q < 32; ++q) {
        int i0 = hf * 64 + 2 * q;
        et[q].x = (_Float16)__expf(trans[i0 * K + u]);
        et[q].y = (_Float16)__expf(trans[(i0 + 1) * K + u]);
    }

    // ---- init: alpha0 = h[b,0,:] + T[SOS,:] ----
    float a0 = hin[(b * T) * K + u] + trans[SOS_IDX * K + u];
    float s  = __expf(a0);
    float W  = s;
#pragma unroll
    for (int off = 2; off <= 32; off <<= 1) W = fmaxf(W, __shfl_xor(W, off));
    float zb = a0;      // Z_b if len == 1
    float c  = 0.0f;
    {
        float vn = s / W;
        float vo = __shfl_xor(vn, 2);
        if ((tid & 3) == 0) {
            UW p; p.h.x = (_Float16)vn; p.h.y = (_Float16)vo;
            vbuf[0][tid >> 2] = p.u;
        }
        if ((tid & 63) == 0) mbuf[0][w] = W;
    }
    __syncthreads();

    if (tid == 0) {
        atomicAdd(out, -(gred[0] + gred[1] + gred[2] + gred[3]) * (1.0f / (float)B));
    }

    // 2-deep prefetch of h rows for state u
    float hv1 = hin[(b * T + 1) * K + u];
    float hv2 = hin[(b * T + 2) * K + u];

    int cur = 0;
    for (int t = 1; t < len; ++t) {
        float hv = hv1;
        hv1 = hv2;
        int tn = t + 2; if (tn >= T) tn = T - 1;
        hv2 = hin[(b * T + tn) * K + u];
        float eh = __expf(hv);

        float4 mm = *((const float4*)mbuf[cur]);            // all 4 wave scales
        float mA = hf ? mm.z : mm.x;                        // chunk 2*hf
        float mB = hf ? mm.w : mm.y;                        // chunk 2*hf+1

        const uint4* vp = (const uint4*)&vbuf[cur][hf * 32];
        float aA0 = 0.f, aA1 = 0.f, aB0 = 0.f, aB1 = 0.f;
#pragma unroll
        for (int r = 0; r < 8; ++r) {
            U4 d; d.v = vp[r];                              // 8 f16 = 8 i-values
            float* acc = (r < 4) ? ((r & 1) ? &aA1 : &aA0)
                                 : ((r & 1) ? &aB1 : &aB0);
            float a = *acc;
            a = dot2(d.h[0], et[4 * r + 0], a);
            a = dot2(d.h[1], et[4 * r + 1], a);
            a = dot2(d.h[2], et[4 * r + 2], a);
            a = dot2(d.h[3], et[4 * r + 3], a);
            *acc = a;
        }
        float sp = fmaf(mA, aA0 + aA1, mB * (aB0 + aB1));
        s = (sp + __shfl_xor(sp, 1)) * eh;                  // pair combine + eh

        zb = c + __logf(s);                                 // alpha_t[u] (f32, pre-rounding)

        W = s;
#pragma unroll
        for (int off = 2; off <= 32; off <<= 1) W = fmaxf(W, __shfl_xor(W, off));
        float G = fmaxf(fmaxf(mm.x, mm.y), fmaxf(mm.z, mm.w));  // uniform

        float vn = s / W;                                   // <= 1, safe in f16
        float vo = __shfl_xor(vn, 2);
        int nxt = cur ^ 1;
        if ((tid & 3) == 0) {
            UW p; p.h.x = (_Float16)vn; p.h.y = (_Float16)vo;
            vbuf[nxt][tid >> 2] = p.u;
        }
        if ((tid & 63) == 0) mbuf[nxt][w] = W / G;
        c += __logf(G);

        __syncthreads();
        cur = nxt;
    }

    if (tid == 2 * EOS_IDX) {                               // owner lane of state EOS
        atomicAdd(out, zb * (1.0f / (float)B));
    }
}

extern "C" void kernel_launch(void* const* d_in, const int* in_sizes, int n_in,
                              void* d_out, int out_size, void* d_ws, size_t ws_size,
                              hipStream_t stream) {
    const float* h       = (const float*)d_in[0];
    const float* trans   = (const float*)d_in[1];
    const int*   y       = (const int*)d_in[2];
    const int*   lengths = (const int*)d_in[3];
    // d_in[4] = mask: derived from lengths instead.
    float* out = (float*)d_out;

    hipMemsetAsync(out, 0, sizeof(float), stream);
    crf_fused<<<B, 2 * K, 0, stream>>>(h, trans, y, lengths, out);
}

// Round 5
// 167.636 us; speedup vs baseline: 1.2465x; 1.2465x over previous
//
#include <hip/hip_runtime.h>
#include <stdint.h>

#define SOS_IDX 1
#define EOS_IDX 2
#define Bb 32
#define Tt 256
#define Kk 128
#define PSTR 136   // padded LDS row stride in ushorts (272 B -> +4 banks/row, kills b128 conflicts)

typedef unsigned short ushort_t;
typedef __attribute__((ext_vector_type(8))) short short8;   // 8 bf16 (4 VGPRs) - MFMA A/B frag
typedef __attribute__((ext_vector_type(4))) float float4v;  // MFMA C/D frag

__device__ __forceinline__ ushort_t f2bf(float x) {
    union { float f; uint32_t u; } c; c.f = x;
    uint32_t u = c.u + 0x7FFFu + ((c.u >> 16) & 1u);        // RNE
    return (ushort_t)(u >> 16);
}
__device__ __forceinline__ float bf2f(ushort_t s) {
    union { uint32_t u; float f; } c; c.u = ((uint32_t)s) << 16;
    return c.f;
}

// ---------------- gold path score (exact f32, unchanged from R3) ----------------
__global__ __launch_bounds__(256) void crf_gold(const float* __restrict__ h,
                                                const float* __restrict__ trans,
                                                const int* __restrict__ y,
                                                const int* __restrict__ lengths,
                                                float* __restrict__ out) {
    const int b = blockIdx.x, t = threadIdx.x;
    const int len = lengths[b];
    float g = 0.0f;
    if (t < len) {
        int yt   = y[b * Tt + t];
        int prev = (t == 0) ? SOS_IDX : y[b * Tt + t - 1];
        g = h[((size_t)b * Tt + t) * Kk + yt] + trans[prev * Kk + yt];
    }
#pragma unroll
    for (int off = 32; off > 0; off >>= 1) g += __shfl_down(g, off);
    __shared__ float ws[4];
    if ((t & 63) == 0) ws[t >> 6] = g;
    __syncthreads();
    if (t == 0) atomicAdd(out, -(ws[0] + ws[1] + ws[2] + ws[3]) * (1.0f / (float)Bb));
}

// ---------------- stage A: per-chunk leaf products ----------------
// block (c, b): Q_{b,c} = prod_{t in [ts,tE)} M_t, M_t[i][j] = e^T[i][j] * e^h[t][j].
// Output Qt = Q^T (bf16, max-normalized to ~1) + log-scale Ls.
__global__ __launch_bounds__(256, 1) void crf_stageA(const float* __restrict__ h,
                                                     const float* __restrict__ trans,
                                                     const int* __restrict__ lengths,
                                                     ushort_t* __restrict__ Qt,
                                                     float* __restrict__ Ls,
                                                     int NC, int CSPAN) {
    const int c = blockIdx.x, b = blockIdx.y;
    const int tid = threadIdx.x;
    const int lane = tid & 63, w = tid >> 6;
    const int len = lengths[b];
    int ts = c * CSPAN; if (ts < 1) ts = 1;
    int te = (c + 1) * CSPAN; if (te > Tt) te = Tt;
    const int tE = te < len ? te : len;
    const size_t qoff = ((size_t)b * NC + c) * (Kk * Kk);

    if (ts >= tE) {   // fully masked chunk -> identity
        for (int e = tid; e < Kk * Kk; e += 256)
            Qt[qoff + e] = ((e >> 7) == (e & 127)) ? (ushort_t)0x3F80 : (ushort_t)0;
        if (tid == 0) Ls[(size_t)b * NC + c] = 0.0f;
        return;
    }

    __shared__ __align__(16) ushort_t s_ett[Kk * PSTR];   // ET^T: [n][k] = e^T[k][n]
    __shared__ __align__(16) ushort_t s_p[2][Kk * PSTR];  // running product, row-major [i][j]
    __shared__ __align__(16) float s_ehb[Kk];
    __shared__ float s_hpart[2];
    __shared__ float s_wmax[4];

    for (int e = tid; e < Kk * Kk; e += 256) {
        int k = e >> 7, n = e & 127;
        s_ett[n * PSTR + k] = f2bf(__expf(trans[e]));
    }
    float hv = 0.0f;
    if (tid < 128) {
        hv = h[((size_t)b * Tt + ts) * Kk + tid];
        float hm = hv;
#pragma unroll
        for (int o = 1; o < 64; o <<= 1) hm = fmaxf(hm, __shfl_xor(hm, o));
        if (lane == 0) s_hpart[w] = hm;
    }
    __syncthreads();                               // ett + hpart ready

    float m = fmaxf(s_hpart[0], s_hpart[1]);
    float L = m;
    if (tid < 128) s_ehb[tid] = __expf(hv - m);

    const int wr = w >> 1, wc = w & 1, c15 = lane & 15, q = lane >> 4;
    __syncthreads();                               // ehb ready

    // hoist B-frags (ET is time-invariant): bfr[kt][ct], 64 VGPRs
    short8 bfr[4][4];
#pragma unroll
    for (int kt = 0; kt < 4; ++kt)
#pragma unroll
        for (int ct = 0; ct < 4; ++ct)
            bfr[kt][ct] = *(const short8*)&s_ett[(wc * 64 + ct * 16 + c15) * PSTR + kt * 32 + q * 8];

    // init P = first leaf: P[i][j] = ETT[j][i] * eh[j]
    {
        float lmax = 0.0f;
        int i = tid & 127, half = tid >> 7;
        for (int j8 = half * 64; j8 < half * 64 + 64; j8 += 8) {
            float4 e0 = *(const float4*)&s_ehb[j8];
            float4 e1 = *(const float4*)&s_ehb[j8 + 4];
            float vv[8];
            vv[0] = bf2f(s_ett[(j8 + 0) * PSTR + i]) * e0.x;
            vv[1] = bf2f(s_ett[(j8 + 1) * PSTR + i]) * e0.y;
            vv[2] = bf2f(s_ett[(j8 + 2) * PSTR + i]) * e0.z;
            vv[3] = bf2f(s_ett[(j8 + 3) * PSTR + i]) * e0.w;
            vv[4] = bf2f(s_ett[(j8 + 4) * PSTR + i]) * e1.x;
            vv[5] = bf2f(s_ett[(j8 + 5) * PSTR + i]) * e1.y;
            vv[6] = bf2f(s_ett[(j8 + 6) * PSTR + i]) * e1.z;
            vv[7] = bf2f(s_ett[(j8 + 7) * PSTR + i]) * e1.w;
            ushort_t pk[8];
#pragma unroll
            for (int r = 0; r < 8; ++r) { lmax = fmaxf(lmax, vv[r]); pk[r] = f2bf(vv[r]); }
            short8 sv;
#pragma unroll
            for (int r = 0; r < 8; ++r) sv[r] = (short)pk[r];
            *(short8*)&s_p[0][i * PSTR + j8] = sv;
        }
#pragma unroll
        for (int o = 1; o < 64; o <<= 1) lmax = fmaxf(lmax, __shfl_xor(lmax, o));
        if (lane == 0) s_wmax[w] = lmax;
    }
    if (tid < 128 && ts + 1 < tE) hv = h[((size_t)b * Tt + ts + 1) * Kk + tid];
    __syncthreads();                               // P0 + wmax ready

    int cur = 0;
    for (int t = ts + 1; t < tE; ++t) {
        float G = fmaxf(fmaxf(s_wmax[0], s_wmax[1]), fmaxf(s_wmax[2], s_wmax[3]));
        float invG = 1.0f / G;
        L += __logf(G);
        if (tid < 128) {
            float hm = hv;
#pragma unroll
            for (int o = 1; o < 64; o <<= 1) hm = fmaxf(hm, __shfl_xor(hm, o));
            if (lane == 0) s_hpart[w] = hm;
        }
        __syncthreads();                           // (1) hpart; wmax reads done
        float mm = fmaxf(s_hpart[0], s_hpart[1]);
        L += mm;
        if (tid < 128) {
            s_ehb[tid] = __expf(hv - mm);
            if (t + 1 < tE) hv = h[((size_t)b * Tt + t + 1) * Kk + tid];  // prefetch
        }
        __syncthreads();                           // (2) ehb ready
        float ehn[4];
#pragma unroll
        for (int ct = 0; ct < 4; ++ct) ehn[ct] = s_ehb[wc * 64 + ct * 16 + c15];

        float4v acc[4][4];
#pragma unroll
        for (int rt = 0; rt < 4; ++rt)
#pragma unroll
            for (int ct = 0; ct < 4; ++ct) acc[rt][ct] = (float4v){0.f, 0.f, 0.f, 0.f};

        const ushort_t* pc = s_p[cur];
#pragma unroll
        for (int kt = 0; kt < 4; ++kt) {
            short8 afr[4];
#pragma unroll
            for (int rt = 0; rt < 4; ++rt)
                afr[rt] = *(const short8*)&pc[(wr * 64 + rt * 16 + c15) * PSTR + kt * 32 + q * 8];
#pragma unroll
            for (int rt = 0; rt < 4; ++rt)
#pragma unroll
                for (int ct = 0; ct < 4; ++ct)
                    acc[rt][ct] = __builtin_amdgcn_mfma_f32_16x16x32_bf16(
                        afr[rt], bfr[kt][ct], acc[rt][ct], 0, 0, 0);
        }
        // epilogue: scale cols by eh[n]*invG, pack bf16, lag-max
        int nxt = cur ^ 1;
        ushort_t* pn = s_p[nxt];
        float lmax = 0.0f;
#pragma unroll
        for (int rt = 0; rt < 4; ++rt) {
            int rowb = wr * 64 + rt * 16 + q * 4;
#pragma unroll
            for (int ct = 0; ct < 4; ++ct) {
                int n = wc * 64 + ct * 16 + c15;
                float sc = ehn[ct] * invG;
#pragma unroll
                for (int r = 0; r < 4; ++r) {
                    float val = acc[rt][ct][r] * sc;
                    lmax = fmaxf(lmax, val);
                    pn[(rowb + r) * PSTR + n] = f2bf(val);
                }
            }
        }
#pragma unroll
        for (int o = 1; o < 64; o <<= 1) lmax = fmaxf(lmax, __shfl_xor(lmax, o));
        if (lane == 0) s_wmax[w] = lmax;
        __syncthreads();                           // (3) P[nxt]+wmax ready
        cur = nxt;
    }

    // dump Q^T, exactly normalized by final max (so stage B sees max==1)
    float Gf = fmaxf(fmaxf(s_wmax[0], s_wmax[1]), fmaxf(s_wmax[2], s_wmax[3]));
    float invGf = 1.0f / Gf;
    L += __logf(Gf);
    const ushort_t* pc = s_p[cur];
#pragma unroll
    for (int r8 = 0; r8 < 8; ++r8) {
        int e8 = (r8 * 256 + tid) * 8;
        int n = e8 >> 7, k0 = e8 & 127;
        ushort_t tmp[8];
#pragma unroll
        for (int r = 0; r < 8; ++r)
            tmp[r] = f2bf(bf2f(pc[(k0 + r) * PSTR + n]) * invGf);
        uint4 gv;
        ushort_t* gp = (ushort_t*)&gv;
#pragma unroll
        for (int r = 0; r < 8; ++r) gp[r] = tmp[r];
        *(uint4*)&Qt[qoff + e8] = gv;
    }
    if (tid == 0) Ls[(size_t)b * NC + c] = L;
}

// ---------------- stage B: combine chunk products, extract Z_b ----------------
__global__ __launch_bounds__(256, 1) void crf_stageB(const float* __restrict__ h,
                                                     const float* __restrict__ trans,
                                                     const ushort_t* __restrict__ Qt,
                                                     const float* __restrict__ Ls,
                                                     float* __restrict__ out, int NC) {
    const int b = blockIdx.x;
    const int tid = threadIdx.x;
    const int lane = tid & 63, w = tid >> 6;
    const int wr = w >> 1, wc = w & 1, c15 = lane & 15, q = lane >> 4;

    __shared__ __align__(16) ushort_t s_bq[Kk * PSTR];
    __shared__ __align__(16) ushort_t s_p[2][Kk * PSTR];
    __shared__ float s_wmax[4];
    __shared__ float s_red[4];

    const size_t lbase = (size_t)b * NC;
    const ushort_t* q0 = Qt + lbase * (Kk * Kk);

    // init P = Q_0 (Qt holds Q^T: P[i][j] = QT[j][i]); one-time uncoalesced ok
    {
        int j = tid & 127, half = tid >> 7;
        for (int i8 = half * 64; i8 < half * 64 + 64; i8 += 8) {
            uint4 g = *(const uint4*)&q0[j * Kk + i8];
            const ushort_t* gs = (const ushort_t*)&g;
#pragma unroll
            for (int r = 0; r < 8; ++r) s_p[0][(i8 + r) * PSTR + j] = gs[r];
        }
    }
    if (tid < 4) s_wmax[tid] = 1.0f;   // stage A normalized Q max to 1
    float L = Ls[lbase];
    __syncthreads();

    int cur = 0;
    for (int c = 1; c < NC; ++c) {
        float G = fmaxf(fmaxf(s_wmax[0], s_wmax[1]), fmaxf(s_wmax[2], s_wmax[3]));
        float invG = 1.0f / G;
        L += __logf(G) + Ls[lbase + c];
        const ushort_t* qc = Qt + (lbase + c) * (Kk * Kk);
#pragma unroll
        for (int r8 = 0; r8 < 8; ++r8) {
            int e8 = (r8 * 256 + tid) * 8;
            int n = e8 >> 7, k0 = e8 & 127;
            uint4 g = *(const uint4*)&qc[e8];      // coalesced
            *(uint4*)&s_bq[n * PSTR + k0] = g;
        }
        __syncthreads();                           // bq ready; wmax reads done

        float4v acc[4][4];
#pragma unroll
        for (int rt = 0; rt < 4; ++rt)
#pragma unroll
            for (int ct = 0; ct < 4; ++ct) acc[rt][ct] = (float4v){0.f, 0.f, 0.f, 0.f};
        const ushort_t* pc = s_p[cur];
#pragma unroll
        for (int kt = 0; kt < 4; ++kt) {
            short8 afr[4], bfr[4];
#pragma unroll
            for (int rt = 0; rt < 4; ++rt)
                afr[rt] = *(const short8*)&pc[(wr * 64 + rt * 16 + c15) * PSTR + kt * 32 + q * 8];
#pragma unroll
            for (int ct = 0; ct < 4; ++ct)
                bfr[ct] = *(const short8*)&s_bq[(wc * 64 + ct * 16 + c15) * PSTR + kt * 32 + q * 8];
#pragma unroll
            for (int rt = 0; rt < 4; ++rt)
#pragma unroll
                for (int ct = 0; ct < 4; ++ct)
                    acc[rt][ct] = __builtin_amdgcn_mfma_f32_16x16x32_bf16(
                        afr[rt], bfr[ct], acc[rt][ct], 0, 0, 0);
        }
        int nxt = cur ^ 1;
        ushort_t* pn = s_p[nxt];
        float lmax = 0.0f;
#pragma unroll
        for (int rt = 0; rt < 4; ++rt) {
            int rowb = wr * 64 + rt * 16 + q * 4;
#pragma unroll
            for (int ct = 0; ct < 4; ++ct) {
                int n = wc * 64 + ct * 16 + c15;
#pragma unroll
                for (int r = 0; r < 4; ++r) {
                    float val = acc[rt][ct][r] * invG;
                    lmax = fmaxf(lmax, val);
                    pn[(rowb + r) * PSTR + n] = f2bf(val);
                }
            }
        }
#pragma unroll
        for (int o = 1; o < 64; o <<= 1) lmax = fmaxf(lmax, __shfl_xor(lmax, o));
        if (lane == 0) s_wmax[w] = lmax;
        __syncthreads();
        cur = nxt;
    }

    // Z_b = m0 + L + log( sum_i exp(alpha0[i]-m0) * P[i][EOS] )
    float a0 = -3.0e38f;
    if (tid < 128) a0 = h[((size_t)b * Tt) * Kk + tid] + trans[SOS_IDX * Kk + tid];
    float hm = a0;
#pragma unroll
    for (int o = 1; o < 64; o <<= 1) hm = fmaxf(hm, __shfl_xor(hm, o));
    if (lane == 0) s_red[w] = hm;
    __syncthreads();
    float m0 = fmaxf(fmaxf(s_red[0], s_red[1]), fmaxf(s_red[2], s_red[3]));
    float contrib = 0.0f;
    if (tid < 128) contrib = __expf(a0 - m0) * bf2f(s_p[cur][tid * PSTR + EOS_IDX]);
#pragma unroll
    for (int o = 1; o < 64; o <<= 1) contrib += __shfl_xor(contrib, o);
    __syncthreads();                               // all m0 reads done before s_red reuse
    if (lane == 0) s_red[w] = contrib;
    __syncthreads();
    if (tid == 0) {
        float tot = s_red[0] + s_red[1] + s_red[2] + s_red[3];
        atomicAdd(out, (m0 + L + __logf(tot)) * (1.0f / (float)Bb));
    }
}

extern "C" void kernel_launch(void* const* d_in, const int* in_sizes, int n_in,
                              void* d_out, int out_size, void* d_ws, size_t ws_size,
                              hipStream_t stream) {
    const float* h       = (const float*)d_in[0];
    const float* trans   = (const float*)d_in[1];
    const int*   y       = (const int*)d_in[2];
    const int*   lengths = (const int*)d_in[3];
    // d_in[4] = mask: derived from lengths instead.
    float* out = (float*)d_out;

    int NC = 8;                                    // 8 chunks of 32 steps
    while (NC > 1) {
        size_t need = (size_t)Bb * NC * Kk * Kk * 2 + (size_t)Bb * NC * 4;
        if (need <= ws_size) break;
        NC >>= 1;                                  // degrade gracefully if ws is small
    }
    int CSPAN = Tt / NC;
    ushort_t* Qt = (ushort_t*)d_ws;
    float* Ls = (float*)((char*)d_ws + (size_t)Bb * NC * Kk * Kk * 2);

    hipMemsetAsync(out, 0, sizeof(float), stream);
    crf_gold<<<Bb, 256, 0, stream>>>(h, trans, y, lengths, out);
    crf_stageA<<<dim3(NC, Bb), 256, 0, stream>>>(h, trans, lengths, Qt, Ls, NC, CSPAN);
    crf_stageB<<<Bb, 256, 0, stream>>>(h, trans, Qt, Ls, out, NC);
}